// Round 2
// baseline (1312.246 us; speedup 1.0000x reference)
//
#include <hip/hip_runtime.h>

typedef _Float16 half8   __attribute__((ext_vector_type(8)));
typedef float    floatx4 __attribute__((ext_vector_type(4)));
typedef unsigned int uint4v __attribute__((ext_vector_type(4)));

#define HW      128
#define CIN     256
#define NCHUNK  8
#define HALO_W  24      // 16 + 2*4
#define HALO_H  16      // 8 + 2*4
#define NPIX    (HALO_W * HALO_H)   // 384
#define PITCH   20      // u32 per pixel: 16 data u32 (32 ci halfs) + 4 pad

// Binarize weights -> f16 (+1/-1), pre-permuted to exact MFMA lane order:
// wp[((((b*8 + chunk)*5 + t)*4 + m)*64 + lane)*8 + j]
//   = sign(w_b[co = m*16 + (lane&15)][ci = chunk*32 + (lane>>4)*8 + j][t])
__global__ void prep_weights(const float* __restrict__ w1,
                             const float* __restrict__ w2,
                             const float* __restrict__ w3,
                             const float* __restrict__ w4,
                             _Float16* __restrict__ wp)
{
    int idx  = blockIdx.x * 256 + threadIdx.x;   // 0 .. 327679
    int j    = idx & 7;
    int lane = (idx >> 3) & 63;
    int m    = (idx >> 9) & 3;
    int r3   = idx >> 11;          // 0..159 = t + 5*(chunk + 8*b)
    int t    = r3 % 5;
    int r4   = r3 / 5;             // chunk + 8*b
    int chunk= r4 & 7;
    int b    = r4 >> 3;
    const float* w = (b == 0) ? w1 : (b == 1) ? w2 : (b == 2) ? w3 : w4;
    int co = m * 16 + (lane & 15);
    int ci = chunk * 32 + (lane >> 4) * 8 + j;
    float v = w[(co * 256 + ci) * 5 + t];
    wp[idx] = (v < 0.0f) ? (_Float16)(-1.0f) : (_Float16)(1.0f);
}

// One WG per (16w x 8h) tile per image. 4 waves = 4 branches.
// Wave computes 64 co x 128 pix via mfma_f32_16x16x32_f16.
//
// R2: async-STAGE split (T14). Per chunk k:
//   stage_write(k)  : pack regs -> LDS (loads landed during previous compute)
//   stage_load(k+1) : issue 48 global loads into regs (fire-and-forget)
//   __syncthreads()
//   compute(k)      : 160 MFMAs — in-flight loads hide under these
// Staged floats held in registers across the MFMA block; all staging arrays
// statically indexed (runtime indexing would go to scratch).
__global__ __launch_bounds__(256, 2)
void bconv_mfma(const float* __restrict__ x,
                const _Float16* __restrict__ wp,
                const float* __restrict__ bb1,
                const float* __restrict__ bb2,
                const float* __restrict__ bb3,
                const float* __restrict__ bb4,
                float* __restrict__ out)
{
    __shared__ __align__(16) unsigned int xs[2 * NPIX * PITCH]; // 61440 B
    __shared__ float bias_s[256];

    const int tid  = threadIdx.x;
    const int w0t  = blockIdx.x * 16;
    const int h0t  = blockIdx.y * 8;
    const int nimg = blockIdx.z;

    {   // stage all 256 biases (branch-major) into LDS
        int br = tid >> 6, i = tid & 63;
        const float* bp = (br == 0) ? bb1 : (br == 1) ? bb2 : (br == 2) ? bb3 : bb4;
        bias_s[tid] = bp[i];
    }

    const int lane = tid & 63;
    const int wave = tid >> 6;          // branch id: 0=H d1, 1=H d2, 2=V d1, 3=V d2
    const int quad = lane >> 4;
    const int wl   = lane & 15;
    const int dil  = (wave & 1) + 1;
    const bool horiz = (wave < 2);

    floatx4 acc[4][8];
    #pragma unroll
    for (int m = 0; m < 4; ++m)
        #pragma unroll
        for (int n = 0; n < 8; ++n)
            acc[m][n] = (floatx4){0.f, 0.f, 0.f, 0.f};

    // per-thread staging geometry (6 tasks: one halo pixel x 8 ci each)
    int s_hh[6], s_ww[6], s_cb[6];
    bool s_ok[6];
    #pragma unroll
    for (int s = 0; s < 6; ++s) {
        int idx = s * 256 + tid;        // 0..1535
        int hh  = idx / 96;             // halo row 0..15
        int rem = idx - hh * 96;
        int cb  = rem / 24;             // ci block of 8: 0..3
        int ww  = rem - cb * 24;        // halo col 0..23
        s_hh[s] = hh; s_ww[s] = ww; s_cb[s] = cb;
        int hg = h0t - 4 + hh;
        int wg = w0t - 4 + ww;
        s_ok[s] = (hg >= 0 && hg < HW && wg >= 0 && wg < HW);
    }

    float vreg[6][8];   // staged values, live across the MFMA block

    auto stage_load = [&](int chunk) {
        #pragma unroll
        for (int s = 0; s < 6; ++s) {
            int hg = h0t - 4 + s_hh[s];
            int wg = w0t - 4 + s_ww[s];
            const float* p = x + (((nimg * CIN + chunk * 32 + s_cb[s] * 8) * HW + hg) * HW + wg);
            #pragma unroll
            for (int jj = 0; jj < 8; ++jj)
                vreg[s][jj] = s_ok[s] ? p[jj * HW * HW] : 0.0f;
        }
    };

    auto stage_write = [&](int buf) {
        unsigned int* xb = &xs[buf * (NPIX * PITCH)];
        #pragma unroll
        for (int s = 0; s < 6; ++s) {
            uint4v u;
            #pragma unroll
            for (int jj = 0; jj < 4; ++jj)
                u[jj] = __builtin_bit_cast(unsigned int,
                            __builtin_amdgcn_cvt_pkrtz(vreg[s][2 * jj], vreg[s][2 * jj + 1]));
            *(uint4v*)&xb[(s_hh[s] * HALO_W + s_ww[s]) * PITCH + s_cb[s] * 4] = u;
        }
    };

    stage_load(0);

    for (int k = 0; k < NCHUNK; ++k) {
        // compute(k-1) read buf[(k-1)&1]; we write buf[k&1] — disjoint, no
        // barrier needed before the write. One barrier per chunk total.
        stage_write(k & 1);
        if (k + 1 < NCHUNK) stage_load(k + 1);   // overlap with compute(k)
        __syncthreads();   // stage(k) visible to all waves
        const unsigned int* xb  = &xs[(k & 1) * (NPIX * PITCH)];
        const _Float16*     wpc = wp + (wave * 8 + k) * (5 * 4 * 64 * 8);

        #pragma unroll
        for (int t = 0; t < 5; ++t) {
            half8 B[8];
            #pragma unroll
            for (int n = 0; n < 8; ++n) {
                int hh, ww;
                if (horiz) { hh = n + 4;                  ww = wl + 4 + (t - 2) * dil; }
                else       { hh = n + 4 + (t - 2) * dil;  ww = wl + 4; }
                B[n] = *(const half8*)&xb[(hh * HALO_W + ww) * PITCH + quad * 4];
            }
            #pragma unroll
            for (int m = 0; m < 4; ++m) {
                half8 A = *(const half8*)(wpc + ((t * 4 + m) * 64 + lane) * 8);
                #pragma unroll
                for (int n = 0; n < 8; ++n)
                    acc[m][n] = __builtin_amdgcn_mfma_f32_16x16x32_f16(A, B[n], acc[m][n], 0, 0, 0);
            }
        }
    }

    // ---- epilogue: bias + store (D: col=lane&15 -> w, row=quad*4+r -> co) ----
    float bv[4][4];
    #pragma unroll
    for (int m = 0; m < 4; ++m)
        #pragma unroll
        for (int r = 0; r < 4; ++r)
            bv[m][r] = bias_s[wave * 64 + m * 16 + quad * 4 + r];

    #pragma unroll
    for (int m = 0; m < 4; ++m) {
        #pragma unroll
        for (int n = 0; n < 8; ++n) {
            int co   = wave * 64 + m * 16 + quad * 4;
            int base = ((nimg * 256 + co) * HW + (h0t + n)) * HW + w0t + wl;
            #pragma unroll
            for (int r = 0; r < 4; ++r)
                out[base + r * HW * HW] = acc[m][n][r] + bv[m][r];
        }
    }
}

extern "C" void kernel_launch(void* const* d_in, const int* in_sizes, int n_in,
                              void* d_out, int out_size, void* d_ws, size_t ws_size,
                              hipStream_t stream)
{
    (void)in_sizes; (void)n_in; (void)out_size; (void)ws_size;
    const float* x  = (const float*)d_in[0];
    const float* w1 = (const float*)d_in[1];
    const float* b1 = (const float*)d_in[2];
    const float* w2 = (const float*)d_in[3];
    const float* b2 = (const float*)d_in[4];
    const float* w3 = (const float*)d_in[5];
    const float* b3 = (const float*)d_in[6];
    const float* w4 = (const float*)d_in[7];
    const float* b4 = (const float*)d_in[8];
    float*    out = (float*)d_out;
    _Float16* wp  = (_Float16*)d_ws;   // 655360 B

    prep_weights<<<1280, 256, 0, stream>>>(w1, w2, w3, w4, wp);

    dim3 grid(128 / 16, 128 / 8, 16);
    bconv_mfma<<<grid, dim3(256), 0, stream>>>(x, wp, b1, b2, b3, b4, out);
}

// Round 3
// 784.309 us; speedup vs baseline: 1.6731x; 1.6731x over previous
//
#include <hip/hip_runtime.h>

typedef _Float16 half8   __attribute__((ext_vector_type(8)));
typedef float    floatx4 __attribute__((ext_vector_type(4)));
typedef unsigned int uint4v __attribute__((ext_vector_type(4)));

#define HW      128
#define CIN     256
#define NCHUNK  8
#define HALO_W  24      // 16 + 2*4
#define HALO_H  16      // 8 + 2*4
#define NPIX    (HALO_W * HALO_H)   // 384
#define PITCH   20      // u32 per pixel: 16 data u32 (32 ci halfs) + 4 pad

// Binarize weights -> f16 (+1/-1), pre-permuted to exact MFMA lane order:
// wp[((((b*8 + chunk)*5 + t)*4 + m)*64 + lane)*8 + j]
//   = sign(w_b[co = m*16 + (lane&15)][ci = chunk*32 + (lane>>4)*8 + j][t])
__global__ void prep_weights(const float* __restrict__ w1,
                             const float* __restrict__ w2,
                             const float* __restrict__ w3,
                             const float* __restrict__ w4,
                             _Float16* __restrict__ wp)
{
    int idx  = blockIdx.x * 256 + threadIdx.x;   // 0 .. 327679
    int j    = idx & 7;
    int lane = (idx >> 3) & 63;
    int m    = (idx >> 9) & 3;
    int r3   = idx >> 11;          // 0..159 = t + 5*(chunk + 8*b)
    int t    = r3 % 5;
    int r4   = r3 / 5;             // chunk + 8*b
    int chunk= r4 & 7;
    int b    = r4 >> 3;
    const float* w = (b == 0) ? w1 : (b == 1) ? w2 : (b == 2) ? w3 : w4;
    int co = m * 16 + (lane & 15);
    int ci = chunk * 32 + (lane >> 4) * 8 + j;
    float v = w[(co * 256 + ci) * 5 + t];
    wp[idx] = (v < 0.0f) ? (_Float16)(-1.0f) : (_Float16)(1.0f);
}

// R3: occupancy restructure. One WG = 512 threads (8 waves) per (16w x 8h)
// tile per image. Wave (branch, h-half): branch = wave>>1, hhalf = wave&1.
// Each wave: 64 co x (16w x 4h) via mfma_f32_16x16x32_f16 -> acc[4][4] = 64
// accumulator regs (R1 had 128, pinning us to 2 waves/SIMD). Target: <=128
// VGPR total at __launch_bounds__(512,4) -> 4 waves/SIMD, 16 waves/CU = 2x TLP
// to hide staging latency. LDS halo (61.4KB dbuf) shared by all 8 waves;
// 2 blocks/CU. R2 lesson: NO registers held across the MFMA phase.
__global__ __launch_bounds__(512, 4)
void bconv_mfma(const float* __restrict__ x,
                const _Float16* __restrict__ wp,
                const float* __restrict__ bb1,
                const float* __restrict__ bb2,
                const float* __restrict__ bb3,
                const float* __restrict__ bb4,
                float* __restrict__ out)
{
    __shared__ __align__(16) unsigned int xs[2 * NPIX * PITCH]; // 61440 B
    __shared__ float bias_s[256];

    const int tid  = threadIdx.x;
    const int w0t  = blockIdx.x * 16;
    const int h0t  = blockIdx.y * 8;
    const int nimg = blockIdx.z;

    if (tid < 256) {   // stage all 256 biases (branch-major) into LDS
        int br = tid >> 6, i = tid & 63;
        const float* bp = (br == 0) ? bb1 : (br == 1) ? bb2 : (br == 2) ? bb3 : bb4;
        bias_s[tid] = bp[i];
    }

    const int lane   = tid & 63;
    const int wave   = tid >> 6;        // 0..7
    const int branch = wave >> 1;       // 0=H d1, 1=H d2, 2=V d1, 3=V d2
    const int hhalf  = wave & 1;        // which 4 output rows
    const int quad   = lane >> 4;
    const int wl     = lane & 15;
    const int dil    = (branch & 1) + 1;
    const bool horiz = (branch < 2);

    floatx4 acc[4][4];                  // [m co-tile][n row] = 64 regs
    #pragma unroll
    for (int m = 0; m < 4; ++m)
        #pragma unroll
        for (int n = 0; n < 4; ++n)
            acc[m][n] = (floatx4){0.f, 0.f, 0.f, 0.f};

    // per-thread staging geometry: 3 tasks (one halo pixel x 8 ci each)
    int s_hh[3], s_ww[3], s_cb[3];
    bool s_ok[3];
    #pragma unroll
    for (int s = 0; s < 3; ++s) {
        int idx = s * 512 + tid;        // 0..1535
        int hh  = idx / 96;             // halo row 0..15
        int rem = idx - hh * 96;
        int cb  = rem / 24;             // ci block of 8: 0..3
        int ww  = rem - cb * 24;        // halo col 0..23
        s_hh[s] = hh; s_ww[s] = ww; s_cb[s] = cb;
        int hg = h0t - 4 + hh;
        int wg = w0t - 4 + ww;
        s_ok[s] = (hg >= 0 && hg < HW && wg >= 0 && wg < HW);
    }

    // Load 24 floats (3 tasks x 8 ci) with full MLP, then pack+write.
    // All temporaries die before the MFMA phase (R2 spill lesson).
    auto stage = [&](int buf, int chunk) {
        float v[3][8];
        #pragma unroll
        for (int s = 0; s < 3; ++s) {
            int hg = h0t - 4 + s_hh[s];
            int wg = w0t - 4 + s_ww[s];
            const float* p = x + (((nimg * CIN + chunk * 32 + s_cb[s] * 8) * HW + hg) * HW + wg);
            #pragma unroll
            for (int jj = 0; jj < 8; ++jj)
                v[s][jj] = s_ok[s] ? p[jj * HW * HW] : 0.0f;
        }
        unsigned int* xb = &xs[buf * (NPIX * PITCH)];
        #pragma unroll
        for (int s = 0; s < 3; ++s) {
            uint4v u;
            #pragma unroll
            for (int jj = 0; jj < 4; ++jj)
                u[jj] = __builtin_bit_cast(unsigned int,
                            __builtin_amdgcn_cvt_pkrtz(v[s][2 * jj], v[s][2 * jj + 1]));
            *(uint4v*)&xb[(s_hh[s] * HALO_W + s_ww[s]) * PITCH + s_cb[s] * 4] = u;
        }
    };

    stage(0, 0);

    for (int k = 0; k < NCHUNK; ++k) {
        __syncthreads();   // stage(k) visible; compute(k-1) reads of this buf done
        const unsigned int* xb  = &xs[(k & 1) * (NPIX * PITCH)];
        const _Float16*     wpc = wp + (branch * 8 + k) * (5 * 4 * 64 * 8);

        #pragma unroll
        for (int t = 0; t < 5; ++t) {
            half8 A[4];
            #pragma unroll
            for (int m = 0; m < 4; ++m)
                A[m] = *(const half8*)(wpc + ((t * 4 + m) * 64 + lane) * 8);
            #pragma unroll
            for (int n = 0; n < 4; ++n) {
                int hh, ww;
                if (horiz) { hh = hhalf * 4 + n + 4;                  ww = wl + 4 + (t - 2) * dil; }
                else       { hh = hhalf * 4 + n + 4 + (t - 2) * dil;  ww = wl + 4; }
                half8 B = *(const half8*)&xb[(hh * HALO_W + ww) * PITCH + quad * 4];
                #pragma unroll
                for (int m = 0; m < 4; ++m)
                    acc[m][n] = __builtin_amdgcn_mfma_f32_16x16x32_f16(A[m], B, acc[m][n], 0, 0, 0);
            }
        }

        // prefetch next chunk into the other buffer; next barrier protects it
        if (k + 1 < NCHUNK) stage((k + 1) & 1, k + 1);
    }

    // ---- epilogue: bias + store (D: col=lane&15 -> w, row=quad*4+r -> co) ----
    float bv[4][4];
    #pragma unroll
    for (int m = 0; m < 4; ++m)
        #pragma unroll
        for (int r = 0; r < 4; ++r)
            bv[m][r] = bias_s[branch * 64 + m * 16 + quad * 4 + r];

    #pragma unroll
    for (int m = 0; m < 4; ++m) {
        #pragma unroll
        for (int n = 0; n < 4; ++n) {
            int co   = branch * 64 + m * 16 + quad * 4;
            int h    = h0t + hhalf * 4 + n;
            int base = ((nimg * 256 + co) * HW + h) * HW + w0t + wl;
            #pragma unroll
            for (int r = 0; r < 4; ++r)
                out[base + r * HW * HW] = acc[m][n][r] + bv[m][r];
        }
    }
}

extern "C" void kernel_launch(void* const* d_in, const int* in_sizes, int n_in,
                              void* d_out, int out_size, void* d_ws, size_t ws_size,
                              hipStream_t stream)
{
    (void)in_sizes; (void)n_in; (void)out_size; (void)ws_size;
    const float* x  = (const float*)d_in[0];
    const float* w1 = (const float*)d_in[1];
    const float* b1 = (const float*)d_in[2];
    const float* w2 = (const float*)d_in[3];
    const float* b2 = (const float*)d_in[4];
    const float* w3 = (const float*)d_in[5];
    const float* b3 = (const float*)d_in[6];
    const float* w4 = (const float*)d_in[7];
    const float* b4 = (const float*)d_in[8];
    float*    out = (float*)d_out;
    _Float16* wp  = (_Float16*)d_ws;   // 655360 B

    prep_weights<<<1280, 256, 0, stream>>>(w1, w2, w3, w4, wp);

    dim3 grid(128 / 16, 128 / 8, 16);
    bconv_mfma<<<grid, dim3(512), 0, stream>>>(x, wp, b1, b2, b3, b4, out);
}

// Round 4
// 731.331 us; speedup vs baseline: 1.7943x; 1.0724x over previous
//
#include <hip/hip_runtime.h>

typedef _Float16 half8   __attribute__((ext_vector_type(8)));
typedef float    floatx4 __attribute__((ext_vector_type(4)));
typedef unsigned int uint4v __attribute__((ext_vector_type(4)));

#define HW      128
#define CIN     256
#define NCHUNK  8
#define HALO_W  24      // 16 + 2*4
#define HALO_H  16      // 8 + 2*4
#define NPIX    (HALO_W * HALO_H)   // 384
#define PITCH   20      // u32 per pixel: 16 data u32 (32 ci halfs) + 4 pad

// Binarize weights -> f16 (+1/-1), pre-permuted to exact MFMA lane order:
// wp[((((b*8 + chunk)*5 + t)*4 + m)*64 + lane)*8 + j]
//   = sign(w_b[co = m*16 + (lane&15)][ci = chunk*32 + (lane>>4)*8 + j][t])
__global__ void prep_weights(const float* __restrict__ w1,
                             const float* __restrict__ w2,
                             const float* __restrict__ w3,
                             const float* __restrict__ w4,
                             _Float16* __restrict__ wp)
{
    int idx  = blockIdx.x * 256 + threadIdx.x;   // 0 .. 327679
    int j    = idx & 7;
    int lane = (idx >> 3) & 63;
    int m    = (idx >> 9) & 3;
    int r3   = idx >> 11;          // 0..159 = t + 5*(chunk + 8*b)
    int t    = r3 % 5;
    int r4   = r3 / 5;             // chunk + 8*b
    int chunk= r4 & 7;
    int b    = r4 >> 3;
    const float* w = (b == 0) ? w1 : (b == 1) ? w2 : (b == 2) ? w3 : w4;
    int co = m * 16 + (lane & 15);
    int ci = chunk * 32 + (lane >> 4) * 8 + j;
    float v = w[(co * 256 + ci) * 5 + t];
    wp[idx] = (v < 0.0f) ? (_Float16)(-1.0f) : (_Float16)(1.0f);
}

// R4: R3's occupancy shape (512 thr, 8 waves, acc[4][4], 4 waves/SIMD) +
//  (a) R0-style PER-TASK staging: geometry recomputed in-loop, each task's
//      load->pack->write chain completes before the next task, so peak
//      liveness = acc(64) + 8 temps + addr ~= 90 < 128-reg budget. R3 spilled
//      ~7 regs/thread (WRITE 532 MB vs 268 ideal) because 24 staging temps +
//      persistent geometry arrays overflowed the (512,4) budget.
//  (b) bijective XCD-chunked block swizzle: each XCD owns a contiguous
//      8x16x2-image tile region, so w- AND h-halo overlap is same-L2
//      (per-chunk slab 2img x 32ci x 128^2 x 4B = 4MB ~ one XCD L2).
__global__ __launch_bounds__(512, 4)
void bconv_mfma(const float* __restrict__ x,
                const _Float16* __restrict__ wp,
                const float* __restrict__ bb1,
                const float* __restrict__ bb2,
                const float* __restrict__ bb3,
                const float* __restrict__ bb4,
                float* __restrict__ out)
{
    __shared__ __align__(16) unsigned int xs[2 * NPIX * PITCH]; // 61440 B
    __shared__ float bias_s[256];

    const int tid = threadIdx.x;

    // XCD-chunked remap: HW dispatches linear id L round-robin (XCD = L%8).
    // s = (L%8)*256 + L/8 gives each XCD a contiguous 256-block region.
    const int L  = blockIdx.x + 8 * (blockIdx.y + 16 * blockIdx.z); // 0..2047
    const int sw = (L & 7) * 256 + (L >> 3);
    const int w0t  = (sw & 7) * 16;         // w-tile 0..7
    const int h0t  = ((sw >> 3) & 15) * 8;  // h-tile 0..15
    const int nimg = sw >> 7;               // image 0..15

    if (tid < 256) {   // stage all 256 biases (branch-major) into LDS
        int br = tid >> 6, i = tid & 63;
        const float* bp = (br == 0) ? bb1 : (br == 1) ? bb2 : (br == 2) ? bb3 : bb4;
        bias_s[tid] = bp[i];
    }

    const int lane   = tid & 63;
    const int wave   = tid >> 6;        // 0..7
    const int branch = wave >> 1;       // 0=H d1, 1=H d2, 2=V d1, 3=V d2
    const int hhalf  = wave & 1;        // which 4 output rows
    const int quad   = lane >> 4;
    const int wl     = lane & 15;
    const int dil    = (branch & 1) + 1;
    const bool horiz = (branch < 2);

    floatx4 acc[4][4];                  // [m co-tile][n row] = 64 regs
    #pragma unroll
    for (int m = 0; m < 4; ++m)
        #pragma unroll
        for (int n = 0; n < 4; ++n)
            acc[m][n] = (floatx4){0.f, 0.f, 0.f, 0.f};

    // Per-task staging: 3 tasks (one halo pixel x 8 ci). Geometry recomputed
    // per task; temps die within the task (R2/R3 spill lesson).
    auto stage = [&](int buf, int chunk) {
        unsigned int* xb = &xs[buf * (NPIX * PITCH)];
        #pragma unroll
        for (int s = 0; s < 3; ++s) {
            int idx = s * 512 + tid;        // 0..1535
            int hh  = idx / 96;             // halo row 0..15
            int rem = idx - hh * 96;
            int cb  = rem / 24;             // ci block of 8: 0..3
            int ww  = rem - cb * 24;        // halo col 0..23
            int hg  = h0t - 4 + hh;
            int wg  = w0t - 4 + ww;
            bool ok = (hg >= 0 && hg < HW && wg >= 0 && wg < HW);
            const float* p = x + (((nimg * CIN + chunk * 32 + cb * 8) * HW + hg) * HW + wg);
            float v[8];
            #pragma unroll
            for (int jj = 0; jj < 8; ++jj)
                v[jj] = ok ? p[jj * HW * HW] : 0.0f;
            uint4v u;
            #pragma unroll
            for (int jj = 0; jj < 4; ++jj)
                u[jj] = __builtin_bit_cast(unsigned int,
                            __builtin_amdgcn_cvt_pkrtz(v[2 * jj], v[2 * jj + 1]));
            *(uint4v*)&xb[(hh * HALO_W + ww) * PITCH + cb * 4] = u;
        }
    };

    stage(0, 0);

    for (int k = 0; k < NCHUNK; ++k) {
        __syncthreads();   // stage(k) visible; compute(k-1) reads of this buf done
        const unsigned int* xb  = &xs[(k & 1) * (NPIX * PITCH)];
        const _Float16*     wpc = wp + (branch * 8 + k) * (5 * 4 * 64 * 8);

        #pragma unroll
        for (int t = 0; t < 5; ++t) {
            half8 A[4];
            #pragma unroll
            for (int m = 0; m < 4; ++m)
                A[m] = *(const half8*)(wpc + ((t * 4 + m) * 64 + lane) * 8);
            #pragma unroll
            for (int n = 0; n < 4; ++n) {
                int hh, ww;
                if (horiz) { hh = hhalf * 4 + n + 4;                  ww = wl + 4 + (t - 2) * dil; }
                else       { hh = hhalf * 4 + n + 4 + (t - 2) * dil;  ww = wl + 4; }
                half8 B = *(const half8*)&xb[(hh * HALO_W + ww) * PITCH + quad * 4];
                #pragma unroll
                for (int m = 0; m < 4; ++m)
                    acc[m][n] = __builtin_amdgcn_mfma_f32_16x16x32_f16(A[m], B, acc[m][n], 0, 0, 0);
            }
        }

        // prefetch next chunk into the other buffer; next barrier protects it
        if (k + 1 < NCHUNK) stage((k + 1) & 1, k + 1);
    }

    // ---- epilogue: bias + store (D: col=lane&15 -> w, row=quad*4+r -> co) ----
    float bv[4][4];
    #pragma unroll
    for (int m = 0; m < 4; ++m)
        #pragma unroll
        for (int r = 0; r < 4; ++r)
            bv[m][r] = bias_s[branch * 64 + m * 16 + quad * 4 + r];

    #pragma unroll
    for (int m = 0; m < 4; ++m) {
        #pragma unroll
        for (int n = 0; n < 4; ++n) {
            int co   = branch * 64 + m * 16 + quad * 4;
            int h    = h0t + hhalf * 4 + n;
            int base = ((nimg * 256 + co) * HW + h) * HW + w0t + wl;
            #pragma unroll
            for (int r = 0; r < 4; ++r)
                out[base + r * HW * HW] = acc[m][n][r] + bv[m][r];
        }
    }
}

extern "C" void kernel_launch(void* const* d_in, const int* in_sizes, int n_in,
                              void* d_out, int out_size, void* d_ws, size_t ws_size,
                              hipStream_t stream)
{
    (void)in_sizes; (void)n_in; (void)out_size; (void)ws_size;
    const float* x  = (const float*)d_in[0];
    const float* w1 = (const float*)d_in[1];
    const float* b1 = (const float*)d_in[2];
    const float* w2 = (const float*)d_in[3];
    const float* b2 = (const float*)d_in[4];
    const float* w3 = (const float*)d_in[5];
    const float* b3 = (const float*)d_in[6];
    const float* w4 = (const float*)d_in[7];
    const float* b4 = (const float*)d_in[8];
    float*    out = (float*)d_out;
    _Float16* wp  = (_Float16*)d_ws;   // 655360 B

    prep_weights<<<1280, 256, 0, stream>>>(w1, w2, w3, w4, wp);

    dim3 grid(128 / 16, 128 / 8, 16);
    bconv_mfma<<<grid, dim3(512), 0, stream>>>(x, wp, b1, b2, b3, b4, out);
}

// Round 5
// 620.511 us; speedup vs baseline: 2.1148x; 1.1786x over previous
//
#include <hip/hip_runtime.h>

typedef _Float16 half8   __attribute__((ext_vector_type(8)));
typedef float    floatx4 __attribute__((ext_vector_type(4)));
typedef unsigned int uint4v __attribute__((ext_vector_type(4)));

#define HW      128
#define CIN     256
#define NCHUNK  8
#define HALO_W  24      // 16 + 2*4
#define HALO_H  16      // 8 + 2*4
#define NPIX    (HALO_W * HALO_H)   // 384
#define PITCH   20      // u32 per pixel: 16 data u32 (32 ci halfs) + 4 pad

// Binarize weights -> f16 (+1/-1), pre-permuted to exact MFMA lane order:
// wp[((((b*8 + chunk)*5 + t)*4 + m)*64 + lane)*8 + j]
//   = sign(w_b[co = m*16 + (lane&15)][ci = chunk*32 + (lane>>4)*8 + j][t])
__global__ void prep_weights(const float* __restrict__ w1,
                             const float* __restrict__ w2,
                             const float* __restrict__ w3,
                             const float* __restrict__ w4,
                             _Float16* __restrict__ wp)
{
    int idx  = blockIdx.x * 256 + threadIdx.x;   // 0 .. 327679
    int j    = idx & 7;
    int lane = (idx >> 3) & 63;
    int m    = (idx >> 9) & 3;
    int r3   = idx >> 11;          // 0..159 = t + 5*(chunk + 8*b)
    int t    = r3 % 5;
    int r4   = r3 / 5;             // chunk + 8*b
    int chunk= r4 & 7;
    int b    = r4 >> 3;
    const float* w = (b == 0) ? w1 : (b == 1) ? w2 : (b == 2) ? w3 : w4;
    int co = m * 16 + (lane & 15);
    int ci = chunk * 32 + (lane >> 4) * 8 + j;
    float v = w[(co * 256 + ci) * 5 + t];
    wp[idx] = (v < 0.0f) ? (_Float16)(-1.0f) : (_Float16)(1.0f);
}

// R5: async-STAGE split, spill-proof (T14 done right).
// Per chunk k: loads for k+1 are ALREADY in flight when compute(k) starts;
// the vmcnt wait (in stage_write's pack) happens only after compute(k), so
// load latency hides under MFMA. Held state = v[3][8] = 24 VGPRs only;
// geometry recomputed per use (no persistent arrays — R3 lesson);
// __launch_bounds__(512,2) gives a 256-reg budget so nothing spills
// (R2/R3 lesson: forced-128 + held state = scratch traffic).
// Keeps R4's XCD-chunked swizzle (FETCH 877->310 MB was real).
__global__ __launch_bounds__(512, 2)
void bconv_mfma(const float* __restrict__ x,
                const _Float16* __restrict__ wp,
                const float* __restrict__ bb1,
                const float* __restrict__ bb2,
                const float* __restrict__ bb3,
                const float* __restrict__ bb4,
                float* __restrict__ out)
{
    __shared__ __align__(16) unsigned int xs[2 * NPIX * PITCH]; // 61440 B
    __shared__ float bias_s[256];

    const int tid = threadIdx.x;

    // XCD-chunked remap: HW dispatches linear id L round-robin (XCD = L%8).
    // s = (L%8)*256 + L/8 gives each XCD a contiguous 256-block region.
    const int L  = blockIdx.x + 8 * (blockIdx.y + 16 * blockIdx.z); // 0..2047
    const int sw = (L & 7) * 256 + (L >> 3);
    const int w0t  = (sw & 7) * 16;         // w-tile 0..7
    const int h0t  = ((sw >> 3) & 15) * 8;  // h-tile 0..15
    const int nimg = sw >> 7;               // image 0..15

    if (tid < 256) {   // stage all 256 biases (branch-major) into LDS
        int br = tid >> 6, i = tid & 63;
        const float* bp = (br == 0) ? bb1 : (br == 1) ? bb2 : (br == 2) ? bb3 : bb4;
        bias_s[tid] = bp[i];
    }

    const int lane   = tid & 63;
    const int wave   = tid >> 6;        // 0..7
    const int branch = wave >> 1;       // 0=H d1, 1=H d2, 2=V d1, 3=V d2
    const int hhalf  = wave & 1;        // which 4 output rows
    const int quad   = lane >> 4;
    const int wl     = lane & 15;
    const int dil    = (branch & 1) + 1;
    const bool horiz = (branch < 2);

    floatx4 acc[4][4];                  // [m co-tile][n row] = 64 regs
    #pragma unroll
    for (int m = 0; m < 4; ++m)
        #pragma unroll
        for (int n = 0; n < 4; ++n)
            acc[m][n] = (floatx4){0.f, 0.f, 0.f, 0.f};

    float v[3][8];   // in-flight staged loads (24 regs, static indexing only)

    // issue 24 global loads for chunk c into v — NO wait here
    auto stage_load = [&](int c) {
        #pragma unroll
        for (int s = 0; s < 3; ++s) {
            int idx = s * 512 + tid;        // 0..1535
            int hh  = idx / 96;             // halo row 0..15
            int rem = idx - hh * 96;
            int cb  = rem / 24;             // ci block of 8: 0..3
            int ww  = rem - cb * 24;        // halo col 0..23
            int hg  = h0t - 4 + hh;
            int wg  = w0t - 4 + ww;
            bool ok = (hg >= 0 && hg < HW && wg >= 0 && wg < HW);
            const float* p = x + (((nimg * CIN + c * 32 + cb * 8) * HW + hg) * HW + wg);
            #pragma unroll
            for (int jj = 0; jj < 8; ++jj)
                v[s][jj] = ok ? p[jj * HW * HW] : 0.0f;
        }
    };

    // pack v -> f16 pairs and write to LDS buffer `buf` (vmcnt wait lands here)
    auto stage_write = [&](int buf) {
        unsigned int* xb = &xs[buf * (NPIX * PITCH)];
        #pragma unroll
        for (int s = 0; s < 3; ++s) {
            int idx = s * 512 + tid;
            int hh  = idx / 96;
            int rem = idx - hh * 96;
            int cb  = rem / 24;
            int ww  = rem - cb * 24;
            uint4v u;
            #pragma unroll
            for (int jj = 0; jj < 4; ++jj)
                u[jj] = __builtin_bit_cast(unsigned int,
                            __builtin_amdgcn_cvt_pkrtz(v[s][2 * jj], v[s][2 * jj + 1]));
            *(uint4v*)&xb[(hh * HALO_W + ww) * PITCH + cb * 4] = u;
        }
    };

    // prologue: chunk 0 staged synchronously; chunk 1 loads left in flight
    stage_load(0);
    stage_write(0);
    stage_load(1);
    __syncthreads();   // buf0 visible to all waves

    for (int k = 0; k < NCHUNK; ++k) {
        const unsigned int* xb  = &xs[(k & 1) * (NPIX * PITCH)];
        const _Float16*     wpc = wp + (branch * 8 + k) * (5 * 4 * 64 * 8);

        #pragma unroll
        for (int t = 0; t < 5; ++t) {
            half8 A[4];
            #pragma unroll
            for (int m = 0; m < 4; ++m)
                A[m] = *(const half8*)(wpc + ((t * 4 + m) * 64 + lane) * 8);
            #pragma unroll
            for (int n = 0; n < 4; ++n) {
                int hh, ww;
                if (horiz) { hh = hhalf * 4 + n + 4;                  ww = wl + 4 + (t - 2) * dil; }
                else       { hh = hhalf * 4 + n + 4 + (t - 2) * dil;  ww = wl + 4; }
                half8 B = *(const half8*)&xb[(hh * HALO_W + ww) * PITCH + quad * 4];
                #pragma unroll
                for (int m = 0; m < 4; ++m)
                    acc[m][n] = __builtin_amdgcn_mfma_f32_16x16x32_f16(A[m], B, acc[m][n], 0, 0, 0);
            }
        }

        if (k + 1 < NCHUNK) {
            // pack+write chunk k+1 (its loads landed during compute(k)).
            // Writing buf[(k+1)&1] is safe: compute(k-1), the last reader of
            // that buffer, finished before the barrier at the end of iter k-1.
            stage_write((k + 1) & 1);
            if (k + 2 < NCHUNK) stage_load(k + 2);   // next loads in flight
            __syncthreads();   // buf[(k+1)&1] visible for compute(k+1)
        }
    }

    // ---- epilogue: bias + store (D: col=lane&15 -> w, row=quad*4+r -> co) ----
    float bv[4][4];
    #pragma unroll
    for (int m = 0; m < 4; ++m)
        #pragma unroll
        for (int r = 0; r < 4; ++r)
            bv[m][r] = bias_s[branch * 64 + m * 16 + quad * 4 + r];

    #pragma unroll
    for (int m = 0; m < 4; ++m) {
        #pragma unroll
        for (int n = 0; n < 4; ++n) {
            int co   = branch * 64 + m * 16 + quad * 4;
            int h    = h0t + hhalf * 4 + n;
            int base = ((nimg * 256 + co) * HW + h) * HW + w0t + wl;
            #pragma unroll
            for (int r = 0; r < 4; ++r)
                out[base + r * HW * HW] = acc[m][n][r] + bv[m][r];
        }
    }
}

extern "C" void kernel_launch(void* const* d_in, const int* in_sizes, int n_in,
                              void* d_out, int out_size, void* d_ws, size_t ws_size,
                              hipStream_t stream)
{
    (void)in_sizes; (void)n_in; (void)out_size; (void)ws_size;
    const float* x  = (const float*)d_in[0];
    const float* w1 = (const float*)d_in[1];
    const float* b1 = (const float*)d_in[2];
    const float* w2 = (const float*)d_in[3];
    const float* b2 = (const float*)d_in[4];
    const float* w3 = (const float*)d_in[5];
    const float* b3 = (const float*)d_in[6];
    const float* w4 = (const float*)d_in[7];
    const float* b4 = (const float*)d_in[8];
    float*    out = (float*)d_out;
    _Float16* wp  = (_Float16*)d_ws;   // 655360 B

    prep_weights<<<1280, 256, 0, stream>>>(w1, w2, w3, w4, wp);

    dim3 grid(128 / 16, 128 / 8, 16);
    bconv_mfma<<<grid, dim3(512), 0, stream>>>(x, wp, b1, b2, b3, b4, out);
}